// Round 9
// baseline (158.755 us; speedup 1.0000x reference)
//
#include <hip/hip_runtime.h>

// SSIM (B=16, C=3, H=W=512, fp32) -> scalar mean.
// v15b: identical resubmission of v15 (round-8 hit GPU-acquisition timeout,
// no verdict). v12 ring + pend prefetch + v9 row-pair-interleaved swizzled LDS.
//  - v14 post-mortem: (256,6) safe but neutral (62 us, occ ~45% at both 5 and
//    6 blk/CU) -> per-step critical path is the limiter, not residency cap.
//  - Fix 1 (latency): pend prefetch -- rows for step s+1 issued at top of
//    step s, consumed one full step later (v10's idea; safe now because
//    #pragma unroll 1 prevents the liveness blowup that killed v10).
//  - Fix 2 (VALU+LDS): LDS element = v2f {rowR[c], rowR+1[c]} at swz8(c+6),
//    4 plane regions x 5248 B = 20.5 KB. Horizontal conv + SSIM become
//    v2f-packed over the row pair: 88 packed FMA/step (was 176 scalar),
//    48 ds_read_b64 (was 56).
//  - Bank check (enumerated): reads/writes are lane-stride-2 elements ->
//    dword index ~ 5l-(l&1) mod 32: every bank exactly 2x per 32-lane
//    phase = conflict-free. (Same proven family as v9.)
//  - (256,5): proven no-spill regime for ring(48,AGPR-shuttled)+pend(16)
//    +roff(12). Falsifier: WRITE_SIZE >10 MB.

typedef float v2f __attribute__((ext_vector_type(2)));

#define IMG_H 512
#define IMG_W 512
#define N_IMG 48                    // B*C
#define WS 11
#define PAD 5
#define CHUNK 16                    // output rows per block
#define NCHUNK (IMG_H / CHUNK)      // 32
#define RING 12                     // rows held in registers
#define PLANE_B 5248                // bytes per plane region (max swz off 5232)
#define NPLANE 4
#define INV_NPX (1.0f / (48.0f * 512.0f * 512.0f))

// swizzled byte offset of element E (element = 8B v2f {rowR, rowR+1})
__device__ __forceinline__ unsigned swz8(int E) {
    return (unsigned)((E + (E >> 2)) * 8);
}
__device__ __forceinline__ v2f vfma(v2f a, v2f b, v2f c) {
    return __builtin_elementwise_fma(a, b, c);
}
__device__ __forceinline__ float uni(float x) {   // force wave-uniform -> SGPR
    return __int_as_float(__builtin_amdgcn_readfirstlane(__float_as_int(x)));
}

__global__ __launch_bounds__(256, 5) void ssim_partial_kernel(
    const float* __restrict__ img1,
    const float* __restrict__ img2,
    const float* __restrict__ window,
    float* __restrict__ out)
{
    __shared__ __align__(16) char lds[NPLANE * PLANE_B];   // 20992 B
    __shared__ float wred[4];

    const int tid = threadIdx.x;
    const int bc  = blockIdx.x;              // image*channel 0..47
    const int r0  = blockIdx.y * CHUNK;
    const int c0  = tid * 2;                 // thread owns cols c0, c0+1

    // 1-D gaussian from window row 5 (w2d[5][j] = g5*g[j]); hoist to SGPRs.
    float g[WS];
    {
        const float g5  = sqrtf(window[5 * WS + 5]);
        const float inv = 1.0f / g5;
#pragma unroll
        for (int j = 0; j < WS; ++j) g[j] = uni(window[5 * WS + j] * inv);
    }
    const float C1v = 0.01f * 0.01f;
    const float C2v = 0.03f * 0.03f;

    const float* __restrict__ p1 = img1 + (size_t)bc * (IMG_H * IMG_W);
    const float* __restrict__ p2 = img2 + (size_t)bc * (IMG_H * IMG_W);

    // zero halo: E in {0..5, 518..523} per plane region (48 elements)
    if (tid < 48) {
        const int pj = tid / 12, h = tid % 12;
        const int E  = (h < 6) ? h : (512 + h);
        *(v2f*)(lds + pj * PLANE_B + swz8(E)) = (v2f)(0.0f);
    }
    __syncthreads();

    // step-invariant LDS byte offsets (element E of col c is c+6)
    const unsigned woffA = swz8(c0 + 6);     // write col c0
    const unsigned woffB = swz8(c0 + 7);     // write col c0+1
    unsigned roff[12];                       // reads: E = c0+1 .. c0+12
#pragma unroll
    for (int m = 0; m < 12; ++m) roff[m] = swz8(c0 + 1 + m);

    // register ring: slot i holds row R-5+i at step base R
    v2f rx1[RING], rx2[RING];
#pragma unroll
    for (int i = 0; i < RING; ++i) { rx1[i] = (v2f)(0.0f); rx2[i] = (v2f)(0.0f); }

    // warm-up: slots 2..11 <- rows r0-5 .. r0+4
#pragma unroll
    for (int i = 0; i < 10; ++i) {
        const int rr = r0 - PAD + i;
        v2f u1 = (v2f)(0.0f), u2 = (v2f)(0.0f);
        if (rr >= 0 && rr < IMG_H) {               // uniform branch
            u1 = *(const v2f*)(p1 + rr * IMG_W + c0);
            u2 = *(const v2f*)(p2 + rr * IMG_W + c0);
        }
        rx1[2 + i] = u1; rx2[2 + i] = u2;
    }
    // prefetch rows r0+5, r0+6 (consumed at step 0)
    v2f pend1[2], pend2[2];
#pragma unroll
    for (int j = 0; j < 2; ++j) {
        const int rr = r0 + PAD + j;
        v2f u1 = (v2f)(0.0f), u2 = (v2f)(0.0f);
        if (rr < IMG_H) {
            u1 = *(const v2f*)(p1 + rr * IMG_W + c0);
            u2 = *(const v2f*)(p2 + rr * IMG_W + c0);
        }
        pend1[j] = u1; pend2[j] = u2;
    }

    float acc = 0.0f;

#pragma unroll 1
    for (int step = 0; step < CHUNK / 2; ++step) {
        const int R = r0 + step * 2;           // output rows R, R+1

        // shift ring by 2; retire pend into slots 10,11
#pragma unroll
        for (int i = 0; i < RING - 2; ++i) { rx1[i] = rx1[i + 2]; rx2[i] = rx2[i + 2]; }
        rx1[10] = pend1[0]; rx2[10] = pend2[0];
        rx1[11] = pend1[1]; rx2[11] = pend2[1];

        // issue NEXT step's loads now (rows R+7, R+8); consumed next step
        if (step + 1 < CHUNK / 2) {            // uniform branch
#pragma unroll
            for (int j = 0; j < 2; ++j) {
                const int rr = R + 7 + j;      // (R+2) + PAD + j
                v2f u1 = (v2f)(0.0f), u2 = (v2f)(0.0f);
                if (rr < IMG_H) {              // uniform branch
                    u1 = *(const v2f*)(p1 + rr * IMG_W + c0);
                    u2 = *(const v2f*)(p2 + rr * IMG_W + c0);
                }
                pend1[j] = u1; pend2[j] = u2;
            }
        }

        // ---- vertical pass A: mu1, mu2 (planes 0,1), rows k=0,1 ----
        v2f va[4][2];
        {
            v2f a0[2] = {(v2f)(0.0f), (v2f)(0.0f)};
            v2f a1[2] = {(v2f)(0.0f), (v2f)(0.0f)};
#pragma unroll
            for (int k = 0; k < 2; ++k)
#pragma unroll
                for (int i = 0; i < WS; ++i) {
                    const v2f w = (v2f)(g[i]);
                    a0[k] = vfma(w, rx1[i + k], a0[k]);
                    a1[k] = vfma(w, rx2[i + k], a1[k]);
                }
            va[0][0] = a0[0]; va[0][1] = a0[1];
            va[1][0] = a1[0]; va[1][1] = a1[1];
        }
        // ---- vertical pass B: S = x1^2+x2^2, P = x1*x2 (planes 2,3) ----
        {
            v2f b0[2] = {(v2f)(0.0f), (v2f)(0.0f)};
            v2f b1[2] = {(v2f)(0.0f), (v2f)(0.0f)};
#pragma unroll
            for (int u = 0; u < RING; ++u) {
                const v2f X1 = rx1[u], X2 = rx2[u];
                const v2f S = vfma(X1, X1, X2 * X2);
                const v2f P = X1 * X2;
                if (u <= 10) {                          // k=0 tap i=u
                    b0[0] = vfma((v2f)(g[u]), S, b0[0]);
                    b1[0] = vfma((v2f)(g[u]), P, b1[0]);
                }
                if (u >= 1) {                           // k=1 tap i=u-1
                    b0[1] = vfma((v2f)(g[u - 1]), S, b0[1]);
                    b1[1] = vfma((v2f)(g[u - 1]), P, b1[1]);
                }
            }
            va[2][0] = b0[0]; va[2][1] = b0[1];
            va[3][0] = b1[0]; va[3][1] = b1[1];
        }
        // repack {col-packed rows} -> {row-pair packed cols} and store
#pragma unroll
        for (int p = 0; p < 4; ++p) {
            char* base = lds + p * PLANE_B;
            *(v2f*)(base + woffA) = (v2f){va[p][0].x, va[p][1].x};
            *(v2f*)(base + woffB) = (v2f){va[p][0].y, va[p][1].y};
        }
        __syncthreads();

        // ---- horizontal conv + SSIM: cols c0, c0+1, rows packed in v2f ----
        v2f hA[4], hB[4];
#pragma unroll
        for (int p = 0; p < 4; ++p) {
            const char* base = lds + p * PLANE_B;
            v2f r[12];
#pragma unroll
            for (int m = 0; m < 12; ++m) r[m] = *(const v2f*)(base + roff[m]);
            v2f sA = (v2f)(0.0f), sB = (v2f)(0.0f);
#pragma unroll
            for (int i = 0; i < WS; ++i) {
                const v2f w = (v2f)(g[i]);
                sA = vfma(w, r[i],     sA);
                sB = vfma(w, r[i + 1], sB);
            }
            hA[p] = sA; hB[p] = sB;
        }
#pragma unroll
        for (int d = 0; d < 2; ++d) {
            const v2f mu1 = d ? hB[0] : hA[0];
            const v2f mu2 = d ? hB[1] : hA[1];
            const v2f hs  = d ? hB[2] : hA[2];
            const v2f hp  = d ? hB[3] : hA[3];
            const v2f mu1s = mu1 * mu1;
            const v2f mu2s = mu2 * mu2;
            const v2f mu12 = mu1 * mu2;
            const v2f sgs  = hs - mu1s - mu2s;       // sigma1^2 + sigma2^2
            const v2f sg12 = hp - mu12;
            const v2f num  = (2.f * mu12 + (v2f)(C1v)) * (2.f * sg12 + (v2f)(C2v));
            const v2f den  = (mu1s + mu2s + (v2f)(C1v)) * (sgs + (v2f)(C2v));
            v2f r = {__builtin_amdgcn_rcpf(den.x), __builtin_amdgcn_rcpf(den.y)};
            r = r * vfma(-den, r, (v2f)(2.0f));      // Newton -> ~1 ulp
            acc = fmaf(num.x, r.x, acc);
            acc = fmaf(num.y, r.y, acc);
        }
        __syncthreads();                             // before LDS overwrite
    }

    // block reduction -> single atomic per block (pre-scaled by 1/Npx)
#pragma unroll
    for (int off = 32; off > 0; off >>= 1)
        acc += __shfl_down(acc, off);
    if ((tid & 63) == 0) wred[tid >> 6] = acc;
    __syncthreads();
    if (tid == 0) {
        const float s = (wred[0] + wred[1]) + (wred[2] + wred[3]);
        atomicAdd(out, s * INV_NPX);
    }
}

extern "C" void kernel_launch(void* const* d_in, const int* in_sizes, int n_in,
                              void* d_out, int out_size, void* d_ws, size_t ws_size,
                              hipStream_t stream) {
    const float* img1   = (const float*)d_in[0];
    const float* img2   = (const float*)d_in[1];
    const float* window = (const float*)d_in[2];
    float* out = (float*)d_out;

    hipMemsetAsync(out, 0, sizeof(float), stream);   // graph-capturable
    dim3 grid(N_IMG, NCHUNK);
    ssim_partial_kernel<<<grid, 256, 0, stream>>>(img1, img2, window, out);
}

// Round 10
// 141.192 us; speedup vs baseline: 1.1244x; 1.1244x over previous
//
#include <hip/hip_runtime.h>

// SSIM (B=16, C=3, H=W=512, fp32) -> scalar mean.
// v16: plane-packed v4f LDS + provably conflict-free x1.5 swizzle.
//  - v15 post-mortem: stride-2 elements under swz8 = 6.3M bank conflicts
//    (enumeration error). Reverted that layout.
//  - v16 element = v4f {mu1,mu2,S,P} of one (col,row) at byte 16*(E+(E>>1)).
//    Reads/writes E = 2t+K -> start bank 12t+c mod 32: 8-lane groups tile
//    all 32 banks exactly once (same class as m134's linear b128 pattern).
//  - Per step: 24 ds_read_b128 + 4 ds_write_b128 (v14: 64 DS insts);
//    horizontal conv = 88 pk-FMA (v14: 176 scalar). One vaddr (48*tid),
//    all offsets compile-time immediates (roff table deleted).
//  - LDS = 2 row-regions x 12608 B = 25.2 KB -> 6 blocks/CU, grid 1536 =
//    exactly 6/CU co-resident.
//  - Ring + pend prefetch + #pragma unroll 1 + (256,6): v14-proven no-spill.
//  - Falsifiers: conflicts >1M -> bank model wrong; WRITE_SIZE >10MB -> spill.

typedef float v2f __attribute__((ext_vector_type(2)));
typedef float v4f __attribute__((ext_vector_type(4)));

#define IMG_H 512
#define IMG_W 512
#define N_IMG 48                    // B*C
#define WS 11
#define PAD 5
#define CHUNK 16                    // output rows per block
#define NCHUNK (IMG_H / CHUNK)      // 32
#define RING 12                     // rows held in registers
#define REG_B 12608                 // bytes per row-region (max swz byte 12560)
#define INV_NPX (1.0f / (48.0f * 512.0f * 512.0f))

__device__ __forceinline__ v2f vfma2(v2f a, v2f b, v2f c) {
    return __builtin_elementwise_fma(a, b, c);
}
__device__ __forceinline__ v4f vfma4(v4f a, v4f b, v4f c) {
    return __builtin_elementwise_fma(a, b, c);
}
__device__ __forceinline__ float uni(float x) {   // force wave-uniform -> SGPR
    return __int_as_float(__builtin_amdgcn_readfirstlane(__float_as_int(x)));
}
// swizzled byte offset of element E (16B v4f): 16 * (E + E/2)
__device__ __forceinline__ unsigned swz16(int E) {
    return (unsigned)((E + (E >> 1)) * 16);
}

__global__ __launch_bounds__(256, 6) void ssim_partial_kernel(
    const float* __restrict__ img1,
    const float* __restrict__ img2,
    const float* __restrict__ window,
    float* __restrict__ out)
{
    __shared__ __align__(16) char lds[2 * REG_B];   // 25216 B
    __shared__ float wred[4];

    const int tid = threadIdx.x;
    const int bc  = blockIdx.x;              // image*channel 0..47
    const int r0  = blockIdx.y * CHUNK;
    const int c0  = tid * 2;                 // thread owns cols c0, c0+1

    // 1-D gaussian from window row 5 (w2d[5][j] = g5*g[j]); hoist to SGPRs.
    float g[WS];
    {
        const float g5  = sqrtf(window[5 * WS + 5]);
        const float inv = 1.0f / g5;
#pragma unroll
        for (int j = 0; j < WS; ++j) g[j] = uni(window[5 * WS + j] * inv);
    }
    const float C1v = 0.01f * 0.01f;
    const float C2v = 0.03f * 0.03f;

    const float* __restrict__ p1 = img1 + (size_t)bc * (IMG_H * IMG_W);
    const float* __restrict__ p2 = img2 + (size_t)bc * (IMG_H * IMG_W);

    // zero halo: E in {0..5, 518..523} per row-region (24 stores)
    if (tid < 24) {
        const int rg = tid / 12, h = tid % 12;
        const int E  = (h < 6) ? h : (512 + h);
        *(v4f*)(lds + rg * REG_B + swz16(E)) = (v4f)(0.0f);
    }
    __syncthreads();

    // all LDS addressing: one vaddr + compile-time immediates.
    // element E = c0 + K (K const per access) -> byte 48*tid + 16*(K + K/2).
    char* lbase = lds + 48 * tid;

    // register ring: slot i holds row R-5+i at step base R
    v2f rx1[RING], rx2[RING];
#pragma unroll
    for (int i = 0; i < RING; ++i) { rx1[i] = (v2f)(0.0f); rx2[i] = (v2f)(0.0f); }

    // warm-up: slots 2..11 <- rows r0-5 .. r0+4
#pragma unroll
    for (int i = 0; i < 10; ++i) {
        const int rr = r0 - PAD + i;
        v2f u1 = (v2f)(0.0f), u2 = (v2f)(0.0f);
        if (rr >= 0 && rr < IMG_H) {               // uniform branch
            u1 = *(const v2f*)(p1 + rr * IMG_W + c0);
            u2 = *(const v2f*)(p2 + rr * IMG_W + c0);
        }
        rx1[2 + i] = u1; rx2[2 + i] = u2;
    }
    // prefetch rows r0+5, r0+6 (consumed at step 0)
    v2f pend1[2], pend2[2];
#pragma unroll
    for (int j = 0; j < 2; ++j) {
        const int rr = r0 + PAD + j;
        v2f u1 = (v2f)(0.0f), u2 = (v2f)(0.0f);
        if (rr < IMG_H) {
            u1 = *(const v2f*)(p1 + rr * IMG_W + c0);
            u2 = *(const v2f*)(p2 + rr * IMG_W + c0);
        }
        pend1[j] = u1; pend2[j] = u2;
    }

    float acc = 0.0f;

#pragma unroll 1
    for (int step = 0; step < CHUNK / 2; ++step) {
        const int R = r0 + step * 2;           // output rows R, R+1

        // shift ring by 2; retire pend into slots 10,11
#pragma unroll
        for (int i = 0; i < RING - 2; ++i) { rx1[i] = rx1[i + 2]; rx2[i] = rx2[i + 2]; }
        rx1[10] = pend1[0]; rx2[10] = pend2[0];
        rx1[11] = pend1[1]; rx2[11] = pend2[1];

        // issue NEXT step's loads now (rows R+7, R+8); consumed next step
        if (step + 1 < CHUNK / 2) {            // uniform branch
#pragma unroll
            for (int j = 0; j < 2; ++j) {
                const int rr = R + 7 + j;      // (R+2) + PAD + j
                v2f u1 = (v2f)(0.0f), u2 = (v2f)(0.0f);
                if (rr < IMG_H) {              // uniform branch
                    u1 = *(const v2f*)(p1 + rr * IMG_W + c0);
                    u2 = *(const v2f*)(p2 + rr * IMG_W + c0);
                }
                pend1[j] = u1; pend2[j] = u2;
            }
        }

        // ---- vertical pass A: mu1, mu2, rows k=0,1 (v2f over col pair) ----
        v2f a0[2] = {(v2f)(0.0f), (v2f)(0.0f)};
        v2f a1[2] = {(v2f)(0.0f), (v2f)(0.0f)};
#pragma unroll
        for (int k = 0; k < 2; ++k)
#pragma unroll
            for (int i = 0; i < WS; ++i) {
                const v2f w = (v2f)(g[i]);
                a0[k] = vfma2(w, rx1[i + k], a0[k]);
                a1[k] = vfma2(w, rx2[i + k], a1[k]);
            }
        // ---- vertical pass B: S = x1^2+x2^2, P = x1*x2 ----
        v2f b0[2] = {(v2f)(0.0f), (v2f)(0.0f)};
        v2f b1[2] = {(v2f)(0.0f), (v2f)(0.0f)};
#pragma unroll
        for (int u = 0; u < RING; ++u) {
            const v2f X1 = rx1[u], X2 = rx2[u];
            const v2f S = vfma2(X1, X1, X2 * X2);
            const v2f P = X1 * X2;
            if (u <= 10) {                          // k=0 tap i=u
                b0[0] = vfma2((v2f)(g[u]), S, b0[0]);
                b1[0] = vfma2((v2f)(g[u]), P, b1[0]);
            }
            if (u >= 1) {                           // k=1 tap i=u-1
                b0[1] = vfma2((v2f)(g[u - 1]), S, b0[1]);
                b1[1] = vfma2((v2f)(g[u - 1]), P, b1[1]);
            }
        }
        // repack -> v4f {mu1,mu2,S,P} per (col,row) and store.
        // col c0  : E = c0+6 -> imm 16*(6+3)  = 144
        // col c0+1: E = c0+7 -> imm 16*(7+3)  = 160
#pragma unroll
        for (int k = 0; k < 2; ++k) {
            const v4f w0 = (v4f){a0[k].x, a1[k].x, b0[k].x, b1[k].x};
            const v4f w1 = (v4f){a0[k].y, a1[k].y, b0[k].y, b1[k].y};
            *(v4f*)(lbase + k * REG_B + 144) = w0;
            *(v4f*)(lbase + k * REG_B + 160) = w1;
        }
        __syncthreads();

        // ---- horizontal conv + SSIM, per output row k ----
        // reads: E = c0+K, K = 1..12 -> imm 16*(K + K/2)
#pragma unroll
        for (int k = 0; k < 2; ++k) {
            v4f hA = (v4f)(0.0f), hB = (v4f)(0.0f);
#pragma unroll
            for (int m = 0; m < 12; ++m) {
                const int K = 1 + m;
                const v4f t = *(const v4f*)(lbase + k * REG_B + 16 * (K + (K >> 1)));
                if (m <= 10) hA = vfma4((v4f)(g[m]),     t, hA);  // col c0
                if (m >= 1)  hB = vfma4((v4f)(g[m - 1]), t, hB);  // col c0+1
            }
#pragma unroll
            for (int d = 0; d < 2; ++d) {
                const v4f h = d ? hB : hA;          // {mu1, mu2, S, P}
                const float mu1 = h.x, mu2 = h.y;
                const float mu1s = mu1 * mu1;
                const float mu2s = mu2 * mu2;
                const float mu12 = mu1 * mu2;
                const float sgs  = h.z - mu1s - mu2s;   // sigma1^2 + sigma2^2
                const float sg12 = h.w - mu12;
                const float num  = (2.f * mu12 + C1v) * (2.f * sg12 + C2v);
                const float den  = (mu1s + mu2s + C1v) * (sgs + C2v);
                float r = __builtin_amdgcn_rcpf(den);
                r = r * fmaf(-den, r, 2.0f);            // Newton -> ~1 ulp
                acc = fmaf(num, r, acc);
            }
        }
        __syncthreads();                                // before LDS overwrite
    }

    // block reduction -> single atomic per block (pre-scaled by 1/Npx)
#pragma unroll
    for (int off = 32; off > 0; off >>= 1)
        acc += __shfl_down(acc, off);
    if ((tid & 63) == 0) wred[tid >> 6] = acc;
    __syncthreads();
    if (tid == 0) {
        const float s = (wred[0] + wred[1]) + (wred[2] + wred[3]);
        atomicAdd(out, s * INV_NPX);
    }
}

extern "C" void kernel_launch(void* const* d_in, const int* in_sizes, int n_in,
                              void* d_out, int out_size, void* d_ws, size_t ws_size,
                              hipStream_t stream) {
    const float* img1   = (const float*)d_in[0];
    const float* img2   = (const float*)d_in[1];
    const float* window = (const float*)d_in[2];
    float* out = (float*)d_out;

    hipMemsetAsync(out, 0, sizeof(float), stream);   // graph-capturable
    dim3 grid(N_IMG, NCHUNK);
    ssim_partial_kernel<<<grid, 256, 0, stream>>>(img1, img2, window, out);
}